// Round 11
// baseline (126.713 us; speedup 1.0000x reference)
//
#include <hip/hip_runtime.h>
#include <math.h>

// OLE loss on MI355X — FUSED single kernel, R26.
// ||X_c||* = trace(sqrt(G_c)), G_c = X_c^T X_c (128x128).
// R26 = R24's engine (best: 64.2us dispatch / 120.0 bench) with Gall built
// by CLASS-SIDE atomics instead of the builder stage:
//   classes atomicAdd their register-resident G_c into Gall right after
//   gram (R15-proven staggered pattern), then flag. Block 64 waits the 64
//   gramdone flags directly. Builders deleted; G_c never touches global.
// Why this and not R25: timeline model (validated on R24's 64.2) —
//   class chain = gram(7) + NS(50) = 57;  block64 = start(11) + NS(50) + 2.
//   Chains balanced with ~6us class-side slack -> shift Gall cost INTO that
//   slack. R25's failure was 96 blocks finishing simultaneously -> 1.57M
//   synchronized RMW burst (WRITE 24.6MB) whose drain delayed the flags;
//   class finishes are staggered (R15: 1M class-side atomics measured free).
// Expected: block64 start 11 -> ~8.5 (slowest gram + ~1.5 drain), dispatch
// ~60-62. If this regresses vs R24 -> structure is at its floor.
// Kept: D-form NS (R24: M=I+D, single-bf16 D, C-init accumulators — LDS
// 107KB, VGPR 116), pipelined gram (R23), peeled final Z-only step (R22;
// guard-in-loop cost 14us — R21), ballot list, flag dataflow.
// Locked-in constraints: 1 block/CU (needs Y+Z+D >= 96KB LDS), 2 waves/SIMD
// (1024t pins VGPR=64 — R16/R17), >128 live regs spill (R20), 3 barriers
// (ping-pong needs 160KB). Lessons: R8 (grid.sync ~50us), R11 (one
// flag/lane), R14+R21 (NITER=6: |w-1|<=1e-5 by k6).

#define N_ROWS 8192
#define DIM    128
#define NCLS   64
#define NB_CE  64
#define NITER  6
#define EPSN   2e-4f
#define LAMBDA_ 0.25f
#define DELTA_  1.0f
#define MAGIC  0x13579BDF   // != 0xAAAAAAAA poison, != 0

typedef __attribute__((ext_vector_type(8))) short s16x8;  // 8 bf16 = 4 VGPR
typedef __attribute__((ext_vector_type(4))) short s16x4;  // 4 bf16
typedef __attribute__((ext_vector_type(4))) float f32x4;

// Scaled-NS ladder: M_k = C1[k]*I - C2[k]*W, C1 = 1.5*sqrt(t), C2 = 0.5*t^1.5.
// t-schedule {2.9, 2.758, 2.13, 1.868, 1.264, 1}; |w-1|<=1e-5 after step 6.
static __device__ const float NS_C1[NITER] =
  {2.554408f, 2.491084f, 2.189178f, 2.050122f, 1.686417f, 1.5f};
static __device__ const float NS_C2[NITER] =
  {2.469261f, 2.290137f, 1.554316f, 1.276543f, 0.710544f, 0.5f};

__device__ __forceinline__ unsigned short f2bf(float f) {   // RNE
  unsigned u = __float_as_uint(f);
  u = (u + 0x7FFFu + ((u >> 16) & 1u)) >> 16;
  return (unsigned short)u;
}
__device__ __forceinline__ float bf2f(unsigned short h) {
  return __uint_as_float(((unsigned)h) << 16);
}

// bf16 LDS: element (i,j) at short-index i*128 + (((j>>3)^(i&15))<<3) + (j&7)
__device__ __forceinline__ int swz_idx(int i, int j) {
  return i * 128 + (((j >> 3) ^ (i & 15)) << 3) + (j & 7);
}

__device__ __forceinline__ s16x8 load_frag(const short* buf, int row0,
                                           int kstep, int lane) {
  int m  = row0 + (lane & 15);
  int kg = kstep * 4 + (lane >> 4);
  return *(const s16x8*)(buf + m * 128 + ((kg ^ (m & 15)) << 3));
}

__device__ __forceinline__ void flag_set(int* p) {
  __threadfence();
  __hip_atomic_store(p, MAGIC, __ATOMIC_RELEASE, __HIP_MEMORY_SCOPE_AGENT);
}
__device__ __forceinline__ void flag_wait(const int* p) {
  while (__hip_atomic_load(p, __ATOMIC_ACQUIRE, __HIP_MEMORY_SCOPE_AGENT) != MAGIC)
    __builtin_amdgcn_s_sleep(8);
}

// ---------------------------------------------------------------------------
// Fused kernel: 129 blocks x 512 threads (8 waves, 2/SIMD, VGPR ~116).
//  0..63   : ballot list -> pipelined gram (regs) -> atomicAdd Gall ->
//            gramdone -> NS(G_c, reg anchor) -> nuc[c] -> nflag
//  64      : wait gramdone[64] -> load Gall -> NS -> wait nflag/ceflag -> out
//  65..128 : CE (512 waves total) -> cepart -> ceflag
// All 129 blocks co-resident (1 block/CU); waits acyclic.
// ---------------------------------------------------------------------------
__global__ __launch_bounds__(512, 1) void ole_fused(const float* __restrict__ feat,
                                                    const int* __restrict__ y,
                                                    const float* __restrict__ logits,
                                                    float* __restrict__ Gall,
                                                    float* __restrict__ nuc,
                                                    float* __restrict__ cepart,
                                                    int* __restrict__ flags,
                                                    float* __restrict__ out) {
  int* gramdone = flags;            // 64
  int* nflag    = flags + 64;       // 64
  int* ceflag   = flags + 128;      // 64

  __shared__ __align__(16) short Yb[DIM * DIM];
  __shared__ __align__(16) short Db[DIM * DIM];   // D = M - I (single bf16)
  __shared__ __align__(16) short Zb[DIM * DIM];
  __shared__ int cnt;

  const int bid  = blockIdx.x;
  const int tid  = threadIdx.x;
  const int lane = tid & 63;
  const int quad = lane >> 4;
  const int wv   = tid >> 6;    // 0..7

  // ---------------- CE blocks (65..128): 512 waves total ----------------
  if (bid > NCLS) {
    const int gwave = (bid - NCLS - 1) * 8 + wv;
    float acc = 0.f;
    for (int row = gwave; row < N_ROWS; row += 512) {
      float v = logits[row * NCLS + lane];
      float mx = v;
      for (int off = 32; off > 0; off >>= 1) mx = fmaxf(mx, __shfl_xor(mx, off, 64));
      float e = expf(v - mx);
      for (int off = 32; off > 0; off >>= 1) e += __shfl_xor(e, off, 64);
      if (lane == 0) {
        int t = y[row];
        acc += (mx + logf(e)) - logits[row * NCLS + t];
      }
    }
    if (lane == 0) cepart[gwave] = acc;
    __syncthreads();
    if (tid == 0) flag_set(&ceflag[bid - NCLS - 1]);
    return;
  }

  // ====================== gram + NS blocks (0..64) ======================
  // 512 threads = 16x32 grid; thread owns 8x4 patch (i0..i0+7, j0..j0+3)
  const int ti = tid >> 5, tj = tid & 31;
  const int i0 = ti * 8,  j0 = tj * 4;

  float tpart = 0.f, fpart = 0.f;
  float4 gs[8];        // block 64 only: Gall slice (NS anchor)
  float  accg[8][4];   // class only: fp32 G_c patch (NS anchor, regs ONLY)

  if (bid < NCLS) {
    // ---- ballot-compacted row list (one lane-0 atomicAdd per 64 rows) ----
    int* list = (int*)Yb;                       // up to 8192 ints (= Yb)
    if (tid == 0) cnt = 0;
    __syncthreads();
#pragma unroll
    for (int t = 0; t < 16; ++t) {
      int row = t * 512 + tid;
      bool hit = (y[row] == bid);
      unsigned long long m = __ballot(hit);
      int base = 0;
      if (lane == 0 && m) base = atomicAdd(&cnt, __popcll(m));
      base = __shfl(base, 0, 64);
      if (hit) {
        int pre = __popcll(m & ((1ull << lane) - 1ull));
        list[base + pre] = row;
      }
    }
    __syncthreads();
    const int n = cnt;

    // ---- pipelined gram: xs ping-pong (2 x 16 x 128 f32 = 16 KB in Db) ----
    float (*xs)[DIM] = (float (*)[DIM])Db;      // [2*16][128]

#pragma unroll
    for (int a = 0; a < 8; ++a)
#pragma unroll
      for (int b = 0; b < 4; ++b) accg[a][b] = 0.f;

    {   // prologue: stage chunk 0 into buffer 0
      float4 v = make_float4(0.f, 0.f, 0.f, 0.f);
      if (ti < n) v = *(const float4*)(feat + (size_t)list[ti] * DIM + j0);
      *(float4*)(&xs[ti][j0]) = v;
    }
    __syncthreads();

    int buf = 0;
    for (int base = 0; base < n; base += 16, buf ^= 1) {
      int li = base + 16 + ti;
      float4 vn = make_float4(0.f, 0.f, 0.f, 0.f);
      if (li < n) vn = *(const float4*)(feat + (size_t)list[li] * DIM + j0);
#pragma unroll
      for (int rw = 0; rw < 16; ++rw) {
        float xi[8], xj[4];
#pragma unroll
        for (int a = 0; a < 8; ++a) xi[a] = xs[buf * 16 + rw][i0 + a];
#pragma unroll
        for (int b = 0; b < 4; ++b) xj[b] = xs[buf * 16 + rw][j0 + b];
#pragma unroll
        for (int a = 0; a < 8; ++a)
#pragma unroll
          for (int b = 0; b < 4; ++b) accg[a][b] = fmaf(xi[a], xj[b], accg[a][b]);
      }
      *(float4*)(&xs[(buf ^ 1) * 16 + ti][j0]) = vn;
      __syncthreads();
    }

    // stats + Gall accumulation (fire-and-forget, staggered across classes;
    // R15-proven: drain at barrier, release flag) — G_c stays in registers.
#pragma unroll
    for (int a = 0; a < 8; ++a)
#pragma unroll
      for (int b = 0; b < 4; ++b) {
        float g = accg[a][b];
        fpart += g * g;
        if (i0 + a == j0 + b) tpart += g;
        atomicAdd(&Gall[(i0 + a) * DIM + (j0 + b)], g);
      }
    __syncthreads();   // each thread drains its own vmcnt at the barrier
    if (tid == 0) flag_set(&gramdone[bid]);
    // list (Yb) / xs (Db) dead from here.
  } else {
    // ---- block 64: wait for all class grams, load Gall ----
    if (tid < NCLS) flag_wait(&gramdone[tid]);  // one flag per lane
    __syncthreads();
    const float4* Gm4 = (const float4*)Gall;
#pragma unroll
    for (int t = 0; t < 8; ++t) {
      int idx4 = tid + 512 * t;
      float4 v = Gm4[idx4];
      gs[t] = v;
      fpart += v.x * v.x + v.y * v.y + v.z * v.z + v.w * v.w;
      int flat = idx4 * 4, i = flat >> 7, jj = flat & 127;
      if (jj <= i && i < jj + 4) tpart += ((const float*)&v)[i - jj];
    }
  }

  // ---- reduce trace / fro2 across 8 waves ----
  for (int off = 32; off > 0; off >>= 1) {
    tpart += __shfl_down(tpart, off, 64);
    fpart += __shfl_down(fpart, off, 64);
  }
  float* redf = (float*)Zb;           // Zb not yet initialized
  if (lane == 0) { redf[wv] = tpart; redf[8 + wv] = fpart; }
  __syncthreads();
  float trace = 0.f, fro2 = 0.f;
#pragma unroll
  for (int w = 0; w < 8; ++w) { trace += redf[w]; fro2 += redf[8 + w]; }
  __syncthreads();                    // redf reads done -> Zb reusable

  float s = sqrtf(fro2);
  if (s < 1e-12f) s = 1.f;
  const float invs = 1.f / s;
  const float eps  = EPSN * trace * invs;

  // ---- init: Y0 = G/s + eps*I (single bf16), Z0 = I ----
  if (bid < NCLS) {
#pragma unroll
    for (int a = 0; a < 8; ++a) {
      int i = i0 + a;
      s16x4 vh;
#pragma unroll
      for (int b = 0; b < 4; ++b) {
        float x = accg[a][b] * invs + ((i == j0 + b) ? eps : 0.f);
        vh[b] = (short)f2bf(x);
      }
      *(s16x4*)(Yb + swz_idx(i, j0)) = vh;
    }
  } else {
#pragma unroll
    for (int t = 0; t < 8; ++t) {
      int idx4 = tid + 512 * t;
      int flat = idx4 * 4, i = flat >> 7, jj = flat & 127;
      s16x4 vh;
#pragma unroll
      for (int e = 0; e < 4; ++e) {
        float x = ((const float*)&gs[t])[e] * invs + ((i == jj + e) ? eps : 0.f);
        vh[e] = (short)f2bf(x);
      }
      *(s16x4*)(Yb + swz_idx(i, jj)) = vh;
    }
  }
  for (int grp = tid; grp < DIM * 16; grp += 512) {
    int i = grp >> 4, g = grp & 15;
    s16x8 v = (s16x8)0;
    if ((i >> 3) == g) v[i & 7] = (short)0x3F80;   // 1.0 bf16
    *(s16x8*)(Zb + i * 128 + ((g ^ (i & 15)) << 3)) = v;
  }
  __syncthreads();

  // 8 waves: 2x4 wave grid, each wave owns a 64x32 output tile (4x2 frags)
  const int wr = wv >> 2;     // 0..1 -> tile-rows 4*wr..4*wr+3
  const int wc = wv & 3;      // 0..3 -> tile-cols 2*wc..2*wc+1

  // ======== main loop: it = 0..NITER-2 (full Y+Z update, D-form) ========
  for (int it = 0; it < NITER - 1; ++it) {
    const float kA = NS_C1[it];
    const float kB = NS_C2[it];

    // --- (a) W = Z*Y ---
    f32x4 acc[4][2];
#pragma unroll
    for (int r = 0; r < 4; ++r)
#pragma unroll
      for (int c2 = 0; c2 < 2; ++c2) acc[r][c2] = (f32x4)0.f;
#pragma unroll
    for (int ks = 0; ks < 4; ++ks) {
      s16x8 a[4], b[2];
#pragma unroll
      for (int r = 0; r < 4; ++r) a[r] = load_frag(Zb, (4 * wr + r) * 16, ks, lane);
#pragma unroll
      for (int c2 = 0; c2 < 2; ++c2) b[c2] = load_frag(Yb, (2 * wc + c2) * 16, ks, lane);
#pragma unroll
      for (int r = 0; r < 4; ++r)
#pragma unroll
        for (int c2 = 0; c2 < 2; ++c2)
          acc[r][c2] = __builtin_amdgcn_mfma_f32_16x16x32_bf16(a[r], b[c2], acc[r][c2], 0, 0, 0);
    }
    // --- (b) D = (kA-1)*I - kB*W, clamp, single bf16, transposed store ---
#pragma unroll
    for (int r = 0; r < 4; ++r) {
      int ibase = (4 * wr + r) * 16 + quad * 4;
      int cg    = ibase >> 3;
#pragma unroll
      for (int c2 = 0; c2 < 2; ++c2) {
        int jg  = (2 * wc + c2) * 16 + (lane & 15);
        int idx = jg * 128 + ((cg ^ (jg & 15)) << 3) + (ibase & 7);
        s16x4 vd;
#pragma unroll
        for (int e = 0; e < 4; ++e) {
          float dv = -kB * acc[r][c2][e] + ((ibase + e == jg) ? (kA - 1.f) : 0.f);
          dv = fminf(fmaxf(dv, -4.f), 4.f);
          vd[e] = (short)f2bf(dv);
        }
        *(s16x4*)(Db + idx) = vd;
      }
    }
    __syncthreads();

    // --- (c) Y' = Y + D*Y, Z' = Z + D*Z (C-init with Y/Z fragments) ---
    f32x4 ay[4][2], az[4][2];
#pragma unroll
    for (int r = 0; r < 4; ++r) {
      int ibase = (4 * wr + r) * 16 + quad * 4;
      int cg    = ibase >> 3;
#pragma unroll
      for (int c2 = 0; c2 < 2; ++c2) {
        int jg  = (2 * wc + c2) * 16 + (lane & 15);
        int idx = jg * 128 + ((cg ^ (jg & 15)) << 3) + (ibase & 7);
        s16x4 yv = *(const s16x4*)(Yb + idx);
        s16x4 zv = *(const s16x4*)(Zb + idx);
#pragma unroll
        for (int e = 0; e < 4; ++e) {
          ay[r][c2][e] = bf2f((unsigned short)yv[e]);
          az[r][c2][e] = bf2f((unsigned short)zv[e]);
        }
      }
    }
#pragma unroll
    for (int ks = 0; ks < 4; ++ks) {
      s16x8 aD[4], bY[2], bZ[2];
#pragma unroll
      for (int r = 0; r < 4; ++r)
        aD[r] = load_frag(Db, (4 * wr + r) * 16, ks, lane);
#pragma unroll
      for (int c2 = 0; c2 < 2; ++c2) {
        int cb = (2 * wc + c2) * 16;
        bY[c2] = load_frag(Yb, cb, ks, lane);
        bZ[c2] = load_frag(Zb, cb, ks, lane);
      }
#pragma unroll
      for (int r = 0; r < 4; ++r)
#pragma unroll
        for (int c2 = 0; c2 < 2; ++c2) {
          ay[r][c2] = __builtin_amdgcn_mfma_f32_16x16x32_bf16(aD[r], bY[c2], ay[r][c2], 0, 0, 0);
          az[r][c2] = __builtin_amdgcn_mfma_f32_16x16x32_bf16(aD[r], bZ[c2], az[r][c2], 0, 0, 0);
        }
    }
    __syncthreads();

    // --- (d) store Y' (single), Z' (single), transposed ---
#pragma unroll
    for (int r = 0; r < 4; ++r) {
      int ibase = (4 * wr + r) * 16 + quad * 4;
      int cg    = ibase >> 3;
#pragma unroll
      for (int c2 = 0; c2 < 2; ++c2) {
        int jg  = (2 * wc + c2) * 16 + (lane & 15);
        int idx = jg * 128 + ((cg ^ (jg & 15)) << 3) + (ibase & 7);
        s16x4 vy, vz;
#pragma unroll
        for (int e = 0; e < 4; ++e) {
          vy[e] = (short)f2bf(ay[r][c2][e]);
          vz[e] = (short)f2bf(az[r][c2][e]);
        }
        *(s16x4*)(Yb + idx) = vy;
        *(s16x4*)(Zb + idx) = vz;
      }
    }
    __syncthreads();
  }

  // ======== peeled final iteration: Z' = Z + D*Z only (Y dead) ========
  {
    const float kA = NS_C1[NITER - 1];
    const float kB = NS_C2[NITER - 1];

    // --- (a) W = Z*Y ---
    f32x4 acc[4][2];
#pragma unroll
    for (int r = 0; r < 4; ++r)
#pragma unroll
      for (int c2 = 0; c2 < 2; ++c2) acc[r][c2] = (f32x4)0.f;
#pragma unroll
    for (int ks = 0; ks < 4; ++ks) {
      s16x8 a[4], b[2];
#pragma unroll
      for (int r = 0; r < 4; ++r) a[r] = load_frag(Zb, (4 * wr + r) * 16, ks, lane);
#pragma unroll
      for (int c2 = 0; c2 < 2; ++c2) b[c2] = load_frag(Yb, (2 * wc + c2) * 16, ks, lane);
#pragma unroll
      for (int r = 0; r < 4; ++r)
#pragma unroll
        for (int c2 = 0; c2 < 2; ++c2)
          acc[r][c2] = __builtin_amdgcn_mfma_f32_16x16x32_bf16(a[r], b[c2], acc[r][c2], 0, 0, 0);
    }
    // --- (b) D = (kA-1)*I - kB*W ---
#pragma unroll
    for (int r = 0; r < 4; ++r) {
      int ibase = (4 * wr + r) * 16 + quad * 4;
      int cg    = ibase >> 3;
#pragma unroll
      for (int c2 = 0; c2 < 2; ++c2) {
        int jg  = (2 * wc + c2) * 16 + (lane & 15);
        int idx = jg * 128 + ((cg ^ (jg & 15)) << 3) + (ibase & 7);
        s16x4 vd;
#pragma unroll
        for (int e = 0; e < 4; ++e) {
          float dv = -kB * acc[r][c2][e] + ((ibase + e == jg) ? (kA - 1.f) : 0.f);
          dv = fminf(fmaxf(dv, -4.f), 4.f);
          vd[e] = (short)f2bf(dv);
        }
        *(s16x4*)(Db + idx) = vd;
      }
    }
    __syncthreads();

    // --- (c) Z' = Z + D*Z only ---
    f32x4 az[4][2];
#pragma unroll
    for (int r = 0; r < 4; ++r) {
      int ibase = (4 * wr + r) * 16 + quad * 4;
      int cg    = ibase >> 3;
#pragma unroll
      for (int c2 = 0; c2 < 2; ++c2) {
        int jg  = (2 * wc + c2) * 16 + (lane & 15);
        int idx = jg * 128 + ((cg ^ (jg & 15)) << 3) + (ibase & 7);
        s16x4 zv = *(const s16x4*)(Zb + idx);
#pragma unroll
        for (int e = 0; e < 4; ++e) az[r][c2][e] = bf2f((unsigned short)zv[e]);
      }
    }
#pragma unroll
    for (int ks = 0; ks < 4; ++ks) {
      s16x8 aD[4], bZ[2];
#pragma unroll
      for (int r = 0; r < 4; ++r)
        aD[r] = load_frag(Db, (4 * wr + r) * 16, ks, lane);
#pragma unroll
      for (int c2 = 0; c2 < 2; ++c2)
        bZ[c2] = load_frag(Zb, (2 * wc + c2) * 16, ks, lane);
#pragma unroll
      for (int r = 0; r < 4; ++r)
#pragma unroll
        for (int c2 = 0; c2 < 2; ++c2)
          az[r][c2] = __builtin_amdgcn_mfma_f32_16x16x32_bf16(aD[r], bZ[c2], az[r][c2], 0, 0, 0);
    }
    __syncthreads();

    // --- (d) store Z' only ---
#pragma unroll
    for (int r = 0; r < 4; ++r) {
      int ibase = (4 * wr + r) * 16 + quad * 4;
      int cg    = ibase >> 3;
#pragma unroll
      for (int c2 = 0; c2 < 2; ++c2) {
        int jg  = (2 * wc + c2) * 16 + (lane & 15);
        int idx = jg * 128 + ((cg ^ (jg & 15)) << 3) + (ibase & 7);
        s16x4 vz;
#pragma unroll
        for (int e = 0; e < 4; ++e) vz[e] = (short)f2bf(az[r][c2][e]);
        *(s16x4*)(Zb + idx) = vz;
      }
    }
    __syncthreads();
  }

  // ---- traces: tr(GZ) (fp32 anchor in regs), tr(Z), tr(Z^3) ----
  float t_gz = 0.f, t_z = 0.f, t_z3 = 0.f;
  if (bid < NCLS) {
#pragma unroll
    for (int a = 0; a < 8; ++a) {
      s16x4 zv = *(const s16x4*)(Zb + swz_idx(i0 + a, j0));
#pragma unroll
      for (int b = 0; b < 4; ++b) t_gz += accg[a][b] * bf2f((unsigned short)zv[b]);
    }
  } else {
#pragma unroll
    for (int t = 0; t < 8; ++t) {
      int idx4 = tid + 512 * t;
      int flat = idx4 * 4, i = flat >> 7, jj = flat & 127;
      s16x4 zv = *(const s16x4*)(Zb + swz_idx(i, jj));
#pragma unroll
      for (int e = 0; e < 4; ++e) t_gz += ((const float*)&gs[t])[e] * bf2f((unsigned short)zv[e]);
    }
  }
  if (tid < DIM) t_z = bf2f((unsigned short)Zb[swz_idx(tid, tid)]);

  {  // U = Z*Z tile-wise; tr(Z^3) = sum U_ij * Z_ji
    f32x4 u[4][2];
#pragma unroll
    for (int r = 0; r < 4; ++r)
#pragma unroll
      for (int c2 = 0; c2 < 2; ++c2) u[r][c2] = (f32x4)0.f;
#pragma unroll
    for (int ks = 0; ks < 4; ++ks) {
      s16x8 a[4], b[2];
#pragma unroll
      for (int r = 0; r < 4; ++r) a[r] = load_frag(Zb, (4 * wr + r) * 16, ks, lane);
#pragma unroll
      for (int c2 = 0; c2 < 2; ++c2) b[c2] = load_frag(Zb, (2 * wc + c2) * 16, ks, lane);
#pragma unroll
      for (int r = 0; r < 4; ++r)
#pragma unroll
        for (int c2 = 0; c2 < 2; ++c2)
          u[r][c2] = __builtin_amdgcn_mfma_f32_16x16x32_bf16(a[r], b[c2], u[r][c2], 0, 0, 0);
    }
#pragma unroll
    for (int r = 0; r < 4; ++r) {
      int ibase = (4 * wr + r) * 16 + quad * 4;
      int cg    = ibase >> 3;
#pragma unroll
      for (int c2 = 0; c2 < 2; ++c2) {
        int jg  = (2 * wc + c2) * 16 + (lane & 15);
        int idx = jg * 128 + ((cg ^ (jg & 15)) << 3) + (ibase & 7);
        s16x4 zt = *(const s16x4*)(Zb + idx);
#pragma unroll
        for (int e = 0; e < 4; ++e) t_z3 += u[r][c2][e] * bf2f((unsigned short)zt[e]);
      }
    }
  }

  for (int off = 32; off > 0; off >>= 1) {
    t_gz += __shfl_down(t_gz, off, 64);
    t_z  += __shfl_down(t_z,  off, 64);
    t_z3 += __shfl_down(t_z3, off, 64);
  }
  __syncthreads();
  float* red = (float*)Db;             // Db dead after last iter
  if (lane == 0) { red[wv] = t_gz; red[8 + wv] = t_z; red[16 + wv] = t_z3; }
  __syncthreads();

  float nuc_own = 0.f;
  if (tid == 0) {
    float gz = 0.f, z1 = 0.f, z3 = 0.f;
#pragma unroll
    for (int w = 0; w < 8; ++w) { gz += red[w]; z1 += red[8 + w]; z3 += red[16 + w]; }
    float trsq = gz * invs + 0.5f * eps * z1 - 0.125f * eps * eps * z3;
    nuc_own = sqrtf(s) * trsq;
    nuc[bid] = nuc_own;
  }

  if (bid < NCLS) {
    if (tid == 0) flag_set(&nflag[bid]);
    return;
  }

  // ======== block 64: final combine (parallel poll, one flag/lane) ========
  if (tid < NCLS)          flag_wait(&nflag[tid]);
  else if (tid < 2 * NCLS) flag_wait(&ceflag[tid - NCLS]);
  __syncthreads();

  float ce2 = cepart[tid];                       // 512 entries, 512 threads
  float vmx = (tid < NCLS) ? fmaxf(nuc[tid], DELTA_) : 0.f;
  for (int off = 32; off > 0; off >>= 1) {
    vmx += __shfl_down(vmx, off, 64);
    ce2 += __shfl_down(ce2, off, 64);
  }
  if (lane == 0) { red[wv] = vmx; red[8 + wv] = ce2; }
  __syncthreads();
  if (tid == 0) {
    float vs = 0.f, cs = 0.f;
#pragma unroll
    for (int w = 0; w < 8; ++w) { vs += red[w]; cs += red[8 + w]; }
    float ole = (vs - nuc_own) * (LAMBDA_ / (float)N_ROWS);
    out[0] = ole + cs / (float)N_ROWS;
  }
}

extern "C" void kernel_launch(void* const* d_in, const int* in_sizes, int n_in,
                              void* d_out, int out_size, void* d_ws, size_t ws_size,
                              hipStream_t stream) {
  const float* logits = (const float*)d_in[0];   // out  [8192,64]
  const float* feat   = (const float*)d_in[1];   // feat [8192,128]
  const int*   yp     = (const int*)d_in[2];     // y    [8192]

  float* Gall   = (float*)d_ws;                  // 16384 f32 (atomic-accumulated)
  int*   flags  = (int*)(Gall + DIM * DIM);      // 256 ints (192 used)
  float* nuc    = (float*)(flags + 256);         // 68
  float* cepart = nuc + 68;                      // 512

  // Zero Gall + flags (workspace is poisoned each run; Gall is the atomic
  // accumulation target; flags independent of re-poison timing). One
  // 66.5 KB memset, graph-capture-safe.
  hipMemsetAsync(d_ws, 0, (DIM * DIM + 256) * sizeof(float), stream);

  ole_fused<<<NCLS + 1 + NB_CE, 512, 0, stream>>>(
      feat, yp, logits, Gall, nuc, cepart, flags, (float*)d_out);
}

// Round 12
// 121.361 us; speedup vs baseline: 1.0441x; 1.0441x over previous
//
#include <hip/hip_runtime.h>
#include <math.h>

// OLE loss on MI355X — FUSED single kernel, R27 == R24 (measured best:
// 64.2us dispatch / 120.0us bench). R25/R26 falsified both alternatives to
// the builder stage: dedicated gall blocks (+4us, synchronized 1.57M RMW
// burst) and class-side atomics (+6us, burst contends with the 64 NS starts
// and delays gramdone). Plain-store G_c + 16-builder tree-sum is the
// measured optimum. Structure is at its floor, every branch measured:
//  - NS chain ~50us: LDS traffic tiling-invariant (R23 derivation); D-form
//    removed redundant algebra (R24); reg-caching spills >128 live (R20);
//    16-wave occupancy pins VGPR=64 (R16/R17); branch-in-loop costs 14us
//    (R21); ping-pong Y/Z needs 160KB LDS (no fit).
//  - block64 start ~11us: builders optimal (R24 < R25, R26).
//  - gram ~5us: pipelined staging, load latency hidden (R23).
//  - arithmetic: NITER=6 minimal (R14/R21); last-iter Y-update dead (R22).
// ||X_c||* = trace(sqrt(G_c)), G_c = X_c^T X_c (128x128), via scaled
// Newton-Schulz in bf16 MFMA with residual form M = I + D.

#define N_ROWS 8192
#define DIM    128
#define NCLS   64
#define NB_CE  64
#define NB_BLD 16
#define NITER  6
#define EPSN   2e-4f
#define LAMBDA_ 0.25f
#define DELTA_  1.0f
#define MAGIC  0x13579BDF   // != 0xAAAAAAAA poison, != 0

typedef __attribute__((ext_vector_type(8))) short s16x8;  // 8 bf16 = 4 VGPR
typedef __attribute__((ext_vector_type(4))) short s16x4;  // 4 bf16
typedef __attribute__((ext_vector_type(4))) float f32x4;

// Scaled-NS ladder: M_k = C1[k]*I - C2[k]*W, C1 = 1.5*sqrt(t), C2 = 0.5*t^1.5.
// t-schedule {2.9, 2.758, 2.13, 1.868, 1.264, 1}; |w-1|<=1e-5 after step 6.
static __device__ const float NS_C1[NITER] =
  {2.554408f, 2.491084f, 2.189178f, 2.050122f, 1.686417f, 1.5f};
static __device__ const float NS_C2[NITER] =
  {2.469261f, 2.290137f, 1.554316f, 1.276543f, 0.710544f, 0.5f};

__device__ __forceinline__ unsigned short f2bf(float f) {   // RNE
  unsigned u = __float_as_uint(f);
  u = (u + 0x7FFFu + ((u >> 16) & 1u)) >> 16;
  return (unsigned short)u;
}
__device__ __forceinline__ float bf2f(unsigned short h) {
  return __uint_as_float(((unsigned)h) << 16);
}

// bf16 LDS: element (i,j) at short-index i*128 + (((j>>3)^(i&15))<<3) + (j&7)
__device__ __forceinline__ int swz_idx(int i, int j) {
  return i * 128 + (((j >> 3) ^ (i & 15)) << 3) + (j & 7);
}

__device__ __forceinline__ s16x8 load_frag(const short* buf, int row0,
                                           int kstep, int lane) {
  int m  = row0 + (lane & 15);
  int kg = kstep * 4 + (lane >> 4);
  return *(const s16x8*)(buf + m * 128 + ((kg ^ (m & 15)) << 3));
}

__device__ __forceinline__ void flag_set(int* p) {
  __threadfence();
  __hip_atomic_store(p, MAGIC, __ATOMIC_RELEASE, __HIP_MEMORY_SCOPE_AGENT);
}
__device__ __forceinline__ void flag_wait(const int* p) {
  while (__hip_atomic_load(p, __ATOMIC_ACQUIRE, __HIP_MEMORY_SCOPE_AGENT) != MAGIC)
    __builtin_amdgcn_s_sleep(8);
}

// ---------------------------------------------------------------------------
// Fused kernel: 145 blocks x 512 threads (8 waves, 2/SIMD, VGPR ~116).
//  0..63   : ballot list -> pipelined LDS-staged Gram -> store G_c ->
//            gramdone -> NS(G_c, reg anchor) -> nuc[c] -> nflag
//  64      : wait gallf[16] -> load Gall -> NS -> wait nflag/ceflag -> out
//  65..128 : CE (512 waves total) -> cepart -> ceflag
//  129..144: wait gramdone[64] -> tree-sum G_c slice -> Gall -> gallf
// ---------------------------------------------------------------------------
__global__ __launch_bounds__(512, 1) void ole_fused(const float* __restrict__ feat,
                                                    const int* __restrict__ y,
                                                    const float* __restrict__ logits,
                                                    float* __restrict__ G,
                                                    float* __restrict__ nuc,
                                                    float* __restrict__ cepart,
                                                    int* __restrict__ flags,
                                                    float* __restrict__ out) {
  int* gramdone = flags;            // 64
  int* gallf    = flags + 64;       // 16
  int* nflag    = flags + 80;       // 64
  int* ceflag   = flags + 144;      // 64

  __shared__ __align__(16) short Yb[DIM * DIM];
  __shared__ __align__(16) short Db[DIM * DIM];   // D = M - I (single bf16)
  __shared__ __align__(16) short Zb[DIM * DIM];
  __shared__ int cnt;

  const int bid  = blockIdx.x;
  const int tid  = threadIdx.x;
  const int lane = tid & 63;
  const int quad = lane >> 4;
  const int wv   = tid >> 6;    // 0..7

  float* Gall = G + (size_t)NCLS * DIM * DIM;

  // ---------------- CE blocks (65..128): 512 waves total ----------------
  if (bid > NCLS && bid <= NCLS + NB_CE) {
    const int gwave = (bid - NCLS - 1) * 8 + wv;
    float acc = 0.f;
    for (int row = gwave; row < N_ROWS; row += 512) {
      float v = logits[row * NCLS + lane];
      float mx = v;
      for (int off = 32; off > 0; off >>= 1) mx = fmaxf(mx, __shfl_xor(mx, off, 64));
      float e = expf(v - mx);
      for (int off = 32; off > 0; off >>= 1) e += __shfl_xor(e, off, 64);
      if (lane == 0) {
        int t = y[row];
        acc += (mx + logf(e)) - logits[row * NCLS + t];
      }
    }
    if (lane == 0) cepart[gwave] = acc;
    __syncthreads();
    if (tid == 0) flag_set(&ceflag[bid - NCLS - 1]);
    return;
  }

  // ---------------- builder blocks (129..144) ----------------
  if (bid > NCLS + NB_CE) {
    const int gb = bid - (NCLS + 1 + NB_CE);        // 0..15
    if (tid < NCLS) flag_wait(&gramdone[tid]);      // one flag per lane
    __syncthreads();
    if (tid < 256) {
      const int idx4 = gb * 256 + tid;              // 16 x 256 = 4096 float4s
      const float4* G4 = (const float4*)G;
      float4 s = make_float4(0.f, 0.f, 0.f, 0.f);
#pragma unroll 8
      for (int c = 0; c < NCLS; ++c) {
        float4 v = G4[(size_t)c * (DIM * DIM / 4) + idx4];
        s.x += v.x; s.y += v.y; s.z += v.z; s.w += v.w;
      }
      ((float4*)Gall)[idx4] = s;
    }
    __syncthreads();
    if (tid == 0) flag_set(&gallf[gb]);
    return;
  }

  // ====================== gram + NS blocks (0..64) ======================
  // 512 threads = 16x32 grid; thread owns 8x4 patch (i0..i0+7, j0..j0+3)
  const int ti = tid >> 5, tj = tid & 31;
  const int i0 = ti * 8,  j0 = tj * 4;

  float tpart = 0.f, fpart = 0.f;
  float4 gs[8];        // block 64 only: Gall slice (NS anchor)
  float  accg[8][4];   // class only: fp32 G_c patch (NS anchor)

  if (bid < NCLS) {
    // ---- ballot-compacted row list (one lane-0 atomicAdd per 64 rows) ----
    int* list = (int*)Yb;                       // up to 8192 ints (= Yb)
    if (tid == 0) cnt = 0;
    __syncthreads();
#pragma unroll
    for (int t = 0; t < 16; ++t) {
      int row = t * 512 + tid;
      bool hit = (y[row] == bid);
      unsigned long long m = __ballot(hit);
      int base = 0;
      if (lane == 0 && m) base = atomicAdd(&cnt, __popcll(m));
      base = __shfl(base, 0, 64);
      if (hit) {
        int pre = __popcll(m & ((1ull << lane) - 1ull));
        list[base + pre] = row;
      }
    }
    __syncthreads();
    const int n = cnt;

    // ---- pipelined gram: xs ping-pong (2 x 16 x 128 f32 = 16 KB in Db) ----
    float (*xs)[DIM] = (float (*)[DIM])Db;      // [2*16][128]

#pragma unroll
    for (int a = 0; a < 8; ++a)
#pragma unroll
      for (int b = 0; b < 4; ++b) accg[a][b] = 0.f;

    {   // prologue: stage chunk 0 into buffer 0
      float4 v = make_float4(0.f, 0.f, 0.f, 0.f);
      if (ti < n) v = *(const float4*)(feat + (size_t)list[ti] * DIM + j0);
      *(float4*)(&xs[ti][j0]) = v;
    }
    __syncthreads();

    int buf = 0;
    for (int base = 0; base < n; base += 16, buf ^= 1) {
      int li = base + 16 + ti;
      float4 vn = make_float4(0.f, 0.f, 0.f, 0.f);
      if (li < n) vn = *(const float4*)(feat + (size_t)list[li] * DIM + j0);
#pragma unroll
      for (int rw = 0; rw < 16; ++rw) {
        float xi[8], xj[4];
#pragma unroll
        for (int a = 0; a < 8; ++a) xi[a] = xs[buf * 16 + rw][i0 + a];
#pragma unroll
        for (int b = 0; b < 4; ++b) xj[b] = xs[buf * 16 + rw][j0 + b];
#pragma unroll
        for (int a = 0; a < 8; ++a)
#pragma unroll
          for (int b = 0; b < 4; ++b) accg[a][b] = fmaf(xi[a], xj[b], accg[a][b]);
      }
      *(float4*)(&xs[(buf ^ 1) * 16 + ti][j0]) = vn;
      __syncthreads();
    }

    // stats + store G_c (plain stores; flag pattern proven by cepart/nuc)
    float* Gc = G + (size_t)bid * DIM * DIM;
#pragma unroll
    for (int a = 0; a < 8; ++a) {
      float4 row;
      float* rp = (float*)&row;
#pragma unroll
      for (int b = 0; b < 4; ++b) {
        float g = accg[a][b];
        rp[b] = g;
        fpart += g * g;
        if (i0 + a == j0 + b) tpart += g;
      }
      *(float4*)(Gc + (size_t)(i0 + a) * DIM + j0) = row;
    }
    __syncthreads();   // all threads' stores drained (vmcnt0 at barrier)
    if (tid == 0) flag_set(&gramdone[bid]);
    // list (Yb) / xs (Db) dead from here.
  } else {
    // ---- block 64: wait for builders, load Gall ----
    if (tid < NB_BLD) flag_wait(&gallf[tid]);   // one flag per lane
    __syncthreads();
    const float4* Gm4 = (const float4*)Gall;
#pragma unroll
    for (int t = 0; t < 8; ++t) {
      int idx4 = tid + 512 * t;
      float4 v = Gm4[idx4];
      gs[t] = v;
      fpart += v.x * v.x + v.y * v.y + v.z * v.z + v.w * v.w;
      int flat = idx4 * 4, i = flat >> 7, jj = flat & 127;
      if (jj <= i && i < jj + 4) tpart += ((const float*)&v)[i - jj];
    }
  }

  // ---- reduce trace / fro2 across 8 waves ----
  for (int off = 32; off > 0; off >>= 1) {
    tpart += __shfl_down(tpart, off, 64);
    fpart += __shfl_down(fpart, off, 64);
  }
  float* redf = (float*)Zb;           // Zb not yet initialized
  if (lane == 0) { redf[wv] = tpart; redf[8 + wv] = fpart; }
  __syncthreads();
  float trace = 0.f, fro2 = 0.f;
#pragma unroll
  for (int w = 0; w < 8; ++w) { trace += redf[w]; fro2 += redf[8 + w]; }
  __syncthreads();                    // redf reads done -> Zb reusable

  float s = sqrtf(fro2);
  if (s < 1e-12f) s = 1.f;
  const float invs = 1.f / s;
  const float eps  = EPSN * trace * invs;

  // ---- init: Y0 = G/s + eps*I (single bf16), Z0 = I ----
  if (bid < NCLS) {
#pragma unroll
    for (int a = 0; a < 8; ++a) {
      int i = i0 + a;
      s16x4 vh;
#pragma unroll
      for (int b = 0; b < 4; ++b) {
        float x = accg[a][b] * invs + ((i == j0 + b) ? eps : 0.f);
        vh[b] = (short)f2bf(x);
      }
      *(s16x4*)(Yb + swz_idx(i, j0)) = vh;
    }
  } else {
#pragma unroll
    for (int t = 0; t < 8; ++t) {
      int idx4 = tid + 512 * t;
      int flat = idx4 * 4, i = flat >> 7, jj = flat & 127;
      s16x4 vh;
#pragma unroll
      for (int e = 0; e < 4; ++e) {
        float x = ((const float*)&gs[t])[e] * invs + ((i == jj + e) ? eps : 0.f);
        vh[e] = (short)f2bf(x);
      }
      *(s16x4*)(Yb + swz_idx(i, jj)) = vh;
    }
  }
  for (int grp = tid; grp < DIM * 16; grp += 512) {
    int i = grp >> 4, g = grp & 15;
    s16x8 v = (s16x8)0;
    if ((i >> 3) == g) v[i & 7] = (short)0x3F80;   // 1.0 bf16
    *(s16x8*)(Zb + i * 128 + ((g ^ (i & 15)) << 3)) = v;
  }
  __syncthreads();

  // 8 waves: 2x4 wave grid, each wave owns a 64x32 output tile (4x2 frags)
  const int wr = wv >> 2;     // 0..1 -> tile-rows 4*wr..4*wr+3
  const int wc = wv & 3;      // 0..3 -> tile-cols 2*wc..2*wc+1

  // ======== main loop: it = 0..NITER-2 (full Y+Z update, D-form) ========
  for (int it = 0; it < NITER - 1; ++it) {
    const float kA = NS_C1[it];
    const float kB = NS_C2[it];

    // --- (a) W = Z*Y ---
    f32x4 acc[4][2];
#pragma unroll
    for (int r = 0; r < 4; ++r)
#pragma unroll
      for (int c2 = 0; c2 < 2; ++c2) acc[r][c2] = (f32x4)0.f;
#pragma unroll
    for (int ks = 0; ks < 4; ++ks) {
      s16x8 a[4], b[2];
#pragma unroll
      for (int r = 0; r < 4; ++r) a[r] = load_frag(Zb, (4 * wr + r) * 16, ks, lane);
#pragma unroll
      for (int c2 = 0; c2 < 2; ++c2) b[c2] = load_frag(Yb, (2 * wc + c2) * 16, ks, lane);
#pragma unroll
      for (int r = 0; r < 4; ++r)
#pragma unroll
        for (int c2 = 0; c2 < 2; ++c2)
          acc[r][c2] = __builtin_amdgcn_mfma_f32_16x16x32_bf16(a[r], b[c2], acc[r][c2], 0, 0, 0);
    }
    // --- (b) D = (kA-1)*I - kB*W, clamp, single bf16, transposed store ---
#pragma unroll
    for (int r = 0; r < 4; ++r) {
      int ibase = (4 * wr + r) * 16 + quad * 4;
      int cg    = ibase >> 3;
#pragma unroll
      for (int c2 = 0; c2 < 2; ++c2) {
        int jg  = (2 * wc + c2) * 16 + (lane & 15);
        int idx = jg * 128 + ((cg ^ (jg & 15)) << 3) + (ibase & 7);
        s16x4 vd;
#pragma unroll
        for (int e = 0; e < 4; ++e) {
          float dv = -kB * acc[r][c2][e] + ((ibase + e == jg) ? (kA - 1.f) : 0.f);
          dv = fminf(fmaxf(dv, -4.f), 4.f);
          vd[e] = (short)f2bf(dv);
        }
        *(s16x4*)(Db + idx) = vd;
      }
    }
    __syncthreads();

    // --- (c) Y' = Y + D*Y, Z' = Z + D*Z (C-init with Y/Z fragments) ---
    f32x4 ay[4][2], az[4][2];
#pragma unroll
    for (int r = 0; r < 4; ++r) {
      int ibase = (4 * wr + r) * 16 + quad * 4;
      int cg    = ibase >> 3;
#pragma unroll
      for (int c2 = 0; c2 < 2; ++c2) {
        int jg  = (2 * wc + c2) * 16 + (lane & 15);
        int idx = jg * 128 + ((cg ^ (jg & 15)) << 3) + (ibase & 7);
        s16x4 yv = *(const s16x4*)(Yb + idx);
        s16x4 zv = *(const s16x4*)(Zb + idx);
#pragma unroll
        for (int e = 0; e < 4; ++e) {
          ay[r][c2][e] = bf2f((unsigned short)yv[e]);
          az[r][c2][e] = bf2f((unsigned short)zv[e]);
        }
      }
    }
#pragma unroll
    for (int ks = 0; ks < 4; ++ks) {
      s16x8 aD[4], bY[2], bZ[2];
#pragma unroll
      for (int r = 0; r < 4; ++r)
        aD[r] = load_frag(Db, (4 * wr + r) * 16, ks, lane);
#pragma unroll
      for (int c2 = 0; c2 < 2; ++c2) {
        int cb = (2 * wc + c2) * 16;
        bY[c2] = load_frag(Yb, cb, ks, lane);
        bZ[c2] = load_frag(Zb, cb, ks, lane);
      }
#pragma unroll
      for (int r = 0; r < 4; ++r)
#pragma unroll
        for (int c2 = 0; c2 < 2; ++c2) {
          ay[r][c2] = __builtin_amdgcn_mfma_f32_16x16x32_bf16(aD[r], bY[c2], ay[r][c2], 0, 0, 0);
          az[r][c2] = __builtin_amdgcn_mfma_f32_16x16x32_bf16(aD[r], bZ[c2], az[r][c2], 0, 0, 0);
        }
    }
    __syncthreads();

    // --- (d) store Y' (single), Z' (single), transposed ---
#pragma unroll
    for (int r = 0; r < 4; ++r) {
      int ibase = (4 * wr + r) * 16 + quad * 4;
      int cg    = ibase >> 3;
#pragma unroll
      for (int c2 = 0; c2 < 2; ++c2) {
        int jg  = (2 * wc + c2) * 16 + (lane & 15);
        int idx = jg * 128 + ((cg ^ (jg & 15)) << 3) + (ibase & 7);
        s16x4 vy, vz;
#pragma unroll
        for (int e = 0; e < 4; ++e) {
          vy[e] = (short)f2bf(ay[r][c2][e]);
          vz[e] = (short)f2bf(az[r][c2][e]);
        }
        *(s16x4*)(Yb + idx) = vy;
        *(s16x4*)(Zb + idx) = vz;
      }
    }
    __syncthreads();
  }

  // ======== peeled final iteration: Z' = Z + D*Z only (Y dead) ========
  {
    const float kA = NS_C1[NITER - 1];
    const float kB = NS_C2[NITER - 1];

    // --- (a) W = Z*Y ---
    f32x4 acc[4][2];
#pragma unroll
    for (int r = 0; r < 4; ++r)
#pragma unroll
      for (int c2 = 0; c2 < 2; ++c2) acc[r][c2] = (f32x4)0.f;
#pragma unroll
    for (int ks = 0; ks < 4; ++ks) {
      s16x8 a[4], b[2];
#pragma unroll
      for (int r = 0; r < 4; ++r) a[r] = load_frag(Zb, (4 * wr + r) * 16, ks, lane);
#pragma unroll
      for (int c2 = 0; c2 < 2; ++c2) b[c2] = load_frag(Yb, (2 * wc + c2) * 16, ks, lane);
#pragma unroll
      for (int r = 0; r < 4; ++r)
#pragma unroll
        for (int c2 = 0; c2 < 2; ++c2)
          acc[r][c2] = __builtin_amdgcn_mfma_f32_16x16x32_bf16(a[r], b[c2], acc[r][c2], 0, 0, 0);
    }
    // --- (b) D = (kA-1)*I - kB*W ---
#pragma unroll
    for (int r = 0; r < 4; ++r) {
      int ibase = (4 * wr + r) * 16 + quad * 4;
      int cg    = ibase >> 3;
#pragma unroll
      for (int c2 = 0; c2 < 2; ++c2) {
        int jg  = (2 * wc + c2) * 16 + (lane & 15);
        int idx = jg * 128 + ((cg ^ (jg & 15)) << 3) + (ibase & 7);
        s16x4 vd;
#pragma unroll
        for (int e = 0; e < 4; ++e) {
          float dv = -kB * acc[r][c2][e] + ((ibase + e == jg) ? (kA - 1.f) : 0.f);
          dv = fminf(fmaxf(dv, -4.f), 4.f);
          vd[e] = (short)f2bf(dv);
        }
        *(s16x4*)(Db + idx) = vd;
      }
    }
    __syncthreads();

    // --- (c) Z' = Z + D*Z only ---
    f32x4 az[4][2];
#pragma unroll
    for (int r = 0; r < 4; ++r) {
      int ibase = (4 * wr + r) * 16 + quad * 4;
      int cg    = ibase >> 3;
#pragma unroll
      for (int c2 = 0; c2 < 2; ++c2) {
        int jg  = (2 * wc + c2) * 16 + (lane & 15);
        int idx = jg * 128 + ((cg ^ (jg & 15)) << 3) + (ibase & 7);
        s16x4 zv = *(const s16x4*)(Zb + idx);
#pragma unroll
        for (int e = 0; e < 4; ++e) az[r][c2][e] = bf2f((unsigned short)zv[e]);
      }
    }
#pragma unroll
    for (int ks = 0; ks < 4; ++ks) {
      s16x8 aD[4], bZ[2];
#pragma unroll
      for (int r = 0; r < 4; ++r)
        aD[r] = load_frag(Db, (4 * wr + r) * 16, ks, lane);
#pragma unroll
      for (int c2 = 0; c2 < 2; ++c2)
        bZ[c2] = load_frag(Zb, (2 * wc + c2) * 16, ks, lane);
#pragma unroll
      for (int r = 0; r < 4; ++r)
#pragma unroll
        for (int c2 = 0; c2 < 2; ++c2)
          az[r][c2] = __builtin_amdgcn_mfma_f32_16x16x32_bf16(aD[r], bZ[c2], az[r][c2], 0, 0, 0);
    }
    __syncthreads();

    // --- (d) store Z' only ---
#pragma unroll
    for (int r = 0; r < 4; ++r) {
      int ibase = (4 * wr + r) * 16 + quad * 4;
      int cg    = ibase >> 3;
#pragma unroll
      for (int c2 = 0; c2 < 2; ++c2) {
        int jg  = (2 * wc + c2) * 16 + (lane & 15);
        int idx = jg * 128 + ((cg ^ (jg & 15)) << 3) + (ibase & 7);
        s16x4 vz;
#pragma unroll
        for (int e = 0; e < 4; ++e) vz[e] = (short)f2bf(az[r][c2][e]);
        *(s16x4*)(Zb + idx) = vz;
      }
    }
    __syncthreads();
  }

  // ---- traces: tr(GZ) (fp32 anchor in regs), tr(Z), tr(Z^3) ----
  float t_gz = 0.f, t_z = 0.f, t_z3 = 0.f;
  if (bid < NCLS) {
#pragma unroll
    for (int a = 0; a < 8; ++a) {
      s16x4 zv = *(const s16x4*)(Zb + swz_idx(i0 + a, j0));
#pragma unroll
      for (int b = 0; b < 4; ++b) t_gz += accg[a][b] * bf2f((unsigned short)zv[b]);
    }
  } else {
#pragma unroll
    for (int t = 0; t < 8; ++t) {
      int idx4 = tid + 512 * t;
      int flat = idx4 * 4, i = flat >> 7, jj = flat & 127;
      s16x4 zv = *(const s16x4*)(Zb + swz_idx(i, jj));
#pragma unroll
      for (int e = 0; e < 4; ++e) t_gz += ((const float*)&gs[t])[e] * bf2f((unsigned short)zv[e]);
    }
  }
  if (tid < DIM) t_z = bf2f((unsigned short)Zb[swz_idx(tid, tid)]);

  {  // U = Z*Z tile-wise; tr(Z^3) = sum U_ij * Z_ji
    f32x4 u[4][2];
#pragma unroll
    for (int r = 0; r < 4; ++r)
#pragma unroll
      for (int c2 = 0; c2 < 2; ++c2) u[r][c2] = (f32x4)0.f;
#pragma unroll
    for (int ks = 0; ks < 4; ++ks) {
      s16x8 a[4], b[2];
#pragma unroll
      for (int r = 0; r < 4; ++r) a[r] = load_frag(Zb, (4 * wr + r) * 16, ks, lane);
#pragma unroll
      for (int c2 = 0; c2 < 2; ++c2) b[c2] = load_frag(Zb, (2 * wc + c2) * 16, ks, lane);
#pragma unroll
      for (int r = 0; r < 4; ++r)
#pragma unroll
        for (int c2 = 0; c2 < 2; ++c2)
          u[r][c2] = __builtin_amdgcn_mfma_f32_16x16x32_bf16(a[r], b[c2], u[r][c2], 0, 0, 0);
    }
#pragma unroll
    for (int r = 0; r < 4; ++r) {
      int ibase = (4 * wr + r) * 16 + quad * 4;
      int cg    = ibase >> 3;
#pragma unroll
      for (int c2 = 0; c2 < 2; ++c2) {
        int jg  = (2 * wc + c2) * 16 + (lane & 15);
        int idx = jg * 128 + ((cg ^ (jg & 15)) << 3) + (ibase & 7);
        s16x4 zt = *(const s16x4*)(Zb + idx);
#pragma unroll
        for (int e = 0; e < 4; ++e) t_z3 += u[r][c2][e] * bf2f((unsigned short)zt[e]);
      }
    }
  }

  for (int off = 32; off > 0; off >>= 1) {
    t_gz += __shfl_down(t_gz, off, 64);
    t_z  += __shfl_down(t_z,  off, 64);
    t_z3 += __shfl_down(t_z3, off, 64);
  }
  __syncthreads();
  float* red = (float*)Db;             // Db dead after last iter
  if (lane == 0) { red[wv] = t_gz; red[8 + wv] = t_z; red[16 + wv] = t_z3; }
  __syncthreads();

  float nuc_own = 0.f;
  if (tid == 0) {
    float gz = 0.f, z1 = 0.f, z3 = 0.f;
#pragma unroll
    for (int w = 0; w < 8; ++w) { gz += red[w]; z1 += red[8 + w]; z3 += red[16 + w]; }
    float trsq = gz * invs + 0.5f * eps * z1 - 0.125f * eps * eps * z3;
    nuc_own = sqrtf(s) * trsq;
    nuc[bid] = nuc_own;
  }

  if (bid < NCLS) {
    if (tid == 0) flag_set(&nflag[bid]);
    return;
  }

  // ======== block 64: final combine (parallel poll, one flag/lane) ========
  if (tid < NCLS)          flag_wait(&nflag[tid]);
  else if (tid < 2 * NCLS) flag_wait(&ceflag[tid - NCLS]);
  __syncthreads();

  float ce2 = cepart[tid];                       // 512 entries, 512 threads
  float vmx = (tid < NCLS) ? fmaxf(nuc[tid], DELTA_) : 0.f;
  for (int off = 32; off > 0; off >>= 1) {
    vmx += __shfl_down(vmx, off, 64);
    ce2 += __shfl_down(ce2, off, 64);
  }
  if (lane == 0) { red[wv] = vmx; red[8 + wv] = ce2; }
  __syncthreads();
  if (tid == 0) {
    float vs = 0.f, cs = 0.f;
#pragma unroll
    for (int w = 0; w < 8; ++w) { vs += red[w]; cs += red[8 + w]; }
    float ole = (vs - nuc_own) * (LAMBDA_ / (float)N_ROWS);
    out[0] = ole + cs / (float)N_ROWS;
  }
}

extern "C" void kernel_launch(void* const* d_in, const int* in_sizes, int n_in,
                              void* d_out, int out_size, void* d_ws, size_t ws_size,
                              hipStream_t stream) {
  const float* logits = (const float*)d_in[0];   // out  [8192,64]
  const float* feat   = (const float*)d_in[1];   // feat [8192,128]
  const int*   yp     = (const int*)d_in[2];     // y    [8192]

  int*   flags  = (int*)d_ws;                    // 256 ints (208 used)
  float* nuc    = (float*)d_ws + 256;            // 68
  float* cepart = nuc + 68;                      // 512
  float* G      = cepart + 512;                  // 65 x 16384 (Gall = idx 64)

  // Zero the flag region (workspace is poisoned each run; keeps flag
  // semantics independent of harness re-poison timing). Graph-capture-safe.
  hipMemsetAsync(d_ws, 0, 256 * sizeof(int), stream);

  ole_fused<<<NCLS + 1 + NB_CE + NB_BLD, 512, 0, stream>>>(
      feat, yp, logits, G, nuc, cepart, flags, (float*)d_out);
}